// Round 4
// baseline (416.170 us; speedup 1.0000x reference)
//
#include <hip/hip_runtime.h>
#include <stdint.h>
#include <stddef.h>

#define LN_EPS 1e-5f

typedef __bf16 bf16;
typedef __bf16 bf16x8 __attribute__((ext_vector_type(8)));
typedef __bf16 bf16x4 __attribute__((ext_vector_type(4)));
typedef float f32x4 __attribute__((ext_vector_type(4)));

// async global->LDS, 16B per lane. LDS dest must be wave-uniform base + lane*16.
#define GL16(gp, lp)                                                                   \
  __builtin_amdgcn_global_load_lds((__attribute__((address_space(1))) uint32_t*)(gp),  \
                                   (__attribute__((address_space(3))) uint32_t*)(lp),  \
                                   16, 0, 0)

// ---------------------------------------------------------------------------
// fp32 -> bf16 convert, 8 floats per thread (16B store). One launch for all.
// ---------------------------------------------------------------------------
#define XV8   3145728           // x:      25,165,824 f32 / 8
#define WQV8  221184            // w_qkv:   1,769,472 f32 / 8
#define WPV8  73728             // w_proj:    589,824 f32 / 8
__global__ __launch_bounds__(256) void cvt_all(const float* __restrict__ x,
                                               const float* __restrict__ wq,
                                               const float* __restrict__ wp,
                                               bf16* __restrict__ xb,
                                               bf16* __restrict__ wqb,
                                               bf16* __restrict__ wpb) {
  int i = blockIdx.x * 256 + threadIdx.x;
  const float* src; bf16* dst; int off;
  if (i < XV8)              { src = x;  dst = xb;  off = i; }
  else if (i < XV8 + WQV8)  { src = wq; dst = wqb; off = i - XV8; }
  else                      { src = wp; dst = wpb; off = i - (XV8 + WQV8); }
  const float4 v0 = ((const float4*)src)[2 * off];
  const float4 v1 = ((const float4*)src)[2 * off + 1];
  bf16x8 o;
  o[0] = (bf16)v0.x; o[1] = (bf16)v0.y; o[2] = (bf16)v0.z; o[3] = (bf16)v0.w;
  o[4] = (bf16)v1.x; o[5] = (bf16)v1.y; o[6] = (bf16)v1.z; o[7] = (bf16)v1.w;
  ((bf16x8*)dst)[off] = o;
}

// ---------------------------------------------------------------------------
// Shared GEMM core, BK=64: C[128x128] tile, A/B row-major [.,768] (B^T GEMM).
// K=768 -> 12 iterations; per iter: 8x GL16, 2x(8 ds_read_b128 + 16 MFMA),
// ONE barrier pair (half the vmcnt(0) drains of BK=32).
// LDS tile [128 rows][8 chunks of 8 bf16]; slot c^(r&7) holds chunk c.
//   staging: lane l -> row (l>>3)+8s, fetches chunk (l&7)^(l>>3), LDS contiguous.
//   frag read slot (qg+4*kh)^(l16&7): each 16-lane quad covers all 8 bank
//   groups 2x -> conflict-free (the pattern that measured 0 conflicts in R2).
// ---------------------------------------------------------------------------
__device__ __forceinline__ void gemm_core_768(const bf16* At, const bf16* Bt,
                                              bf16* lA, bf16* lB,
                                              f32x4 acc[4][4]) {
  const int tid  = threadIdx.x;
  const int wave = tid >> 6;
  const int lane = tid & 63;
  const int l16  = lane & 15;

  // staging: wave w covers rows [32w, 32w+32); 4 insts of 8 rows x 128B each.
  const int r8 = lane >> 3;                       // 0..7
  const int gq = (lane & 7) ^ r8;                 // swizzled chunk to fetch
  const int srow0 = wave * 32 + r8;
  const bf16* gA = At + srow0 * 768 + gq * 8;
  const bf16* gB = Bt + srow0 * 768 + gq * 8;
  bf16* sA = lA + wave * 2048 + lane * 8;         // +512 per inst (8 rows x 64)
  bf16* sB = lB + wave * 2048 + lane * 8;

  const int wm = (wave & 1) * 64;
  const int wn = (wave >> 1) * 64;
  const int qg = lane >> 4;
  // element offset of swizzled chunk for k-half 0 and 1
  const int rd0 = ((qg)     ^ (l16 & 7)) * 8;
  const int rd1 = ((qg + 4) ^ (l16 & 7)) * 8;

  for (int kt = 0; kt < 768; kt += 64) {
#pragma unroll
    for (int s = 0; s < 4; s++) {
      GL16(gA + kt + s * 8 * 768, sA + s * 512);
      GL16(gB + kt + s * 8 * 768, sB + s * 512);
    }
    __syncthreads();   // drains vmcnt(0); staged data visible

#pragma unroll
    for (int kh = 0; kh < 2; kh++) {
      const int rd = kh ? rd1 : rd0;
      bf16x8 aF[4], bF[4];
#pragma unroll
      for (int i = 0; i < 4; i++)
        aF[i] = *(const bf16x8*)(lA + (wm + i * 16 + l16) * 64 + rd);
#pragma unroll
      for (int j = 0; j < 4; j++)
        bF[j] = *(const bf16x8*)(lB + (wn + j * 16 + l16) * 64 + rd);

#pragma unroll
      for (int i = 0; i < 4; i++)
#pragma unroll
        for (int j = 0; j < 4; j++)
          acc[i][j] = __builtin_amdgcn_mfma_f32_16x16x32_bf16(aF[i], bF[j], acc[i][j], 0, 0, 0);
    }

    __syncthreads();   // all waves done reading before next stage overwrites
  }
}

// ---------------------------------------------------------------------------
// Pass 1: k/v GEMM + fused p2-weighted k*v reduction. Grid (12 h, 256 mblk).
// Cols 0..63 = k head h, 64..127 = v head h (B rows spliced per wave).
// Epilogue: acc -> bf16 in padded LDS, reduce sum_n p2*k*v -> partials.
// ---------------------------------------------------------------------------
__global__ __launch_bounds__(256) void kv_gemm_reduce(const bf16* __restrict__ A,
                                                      const bf16* __restrict__ B,
                                                      const float* __restrict__ p2,
                                                      float* __restrict__ partials) {
  // staging needs 2 x 128x64 bf16 = 32KB; epilogue k/v tile [2][128][68] bf16
  // = 34.8KB aliased on top (dead after core's final barrier).
  __shared__ __align__(16) bf16 sKV[2 * 128 * 68];
  __shared__ float red[4][64];
  bf16* lA = sKV;                 // 8192 elements
  bf16* lB = sKV + 8192;          // 8192 elements

  const int h    = blockIdx.x;
  const int mblk = blockIdx.y;
  const int m0   = mblk * 128;
  const int tid  = threadIdx.x, wave = tid >> 6, lane = tid & 63;

  // waves 0,1 stage k rows (w_qkv rows 768+64h ..+64); waves 2,3 stage v rows
  // (1536+64h ..+64). Core uses srow = wave*32+., so pre-bias v base by -64 rows.
  const bf16* Bt = B + (size_t)(wave < 2 ? (768 + h * 64) : (1536 + h * 64 - 64)) * 768;

  f32x4 acc[4][4] = {};
  gemm_core_768(A + (size_t)m0 * 768, Bt, sKV /*lA*/, lB, acc);

  // ---- epilogue: spill tiles to LDS as bf16 (same quantization as the
  // materializing path), padded stride 68 for conflict-free access.
  const int kv    = wave >> 1;                      // 0 = k, 1 = v
  const int row_l = (wave & 1) * 64 + (lane >> 4) * 4;
  const int d_l   = lane & 15;
  bf16* sT = sKV + kv * (128 * 68);
#pragma unroll
  for (int i = 0; i < 4; i++)
#pragma unroll
    for (int j = 0; j < 4; j++)
#pragma unroll
      for (int r = 0; r < 4; r++)
        sT[(row_l + i * 16 + r) * 68 + j * 16 + d_l] = (bf16)acc[i][j][r];
  __syncthreads();

  // ---- reduce over the 128 rows: thread (d = tid&63, chunk = tid>>6) sums 32
  const int d  = tid & 63;
  const int ch = tid >> 6;
  const int n_base = (m0 & 4095) + ch * 32;
  const float* pw = p2 + h * 4096 + n_base;
  const bf16* sk = sKV + (ch * 32) * 68 + d;
  const bf16* sv = sk + 128 * 68;
  float s = 0.f;
#pragma unroll 8
  for (int n = 0; n < 32; n++)
    s += pw[n] * (float)sk[n * 68] * (float)sv[n * 68];
  red[ch][d] = s;
  __syncthreads();
  if (tid < 64) {
    partials[((size_t)mblk * 12 + h) * 64 + tid] =
        red[0][tid] + red[1][tid] + red[2][tid] + red[3][tid];
  }
}

// ---------------------------------------------------------------------------
// Stage 2: sum the 32 per-mblk partials of each batch, then LayerNorm over d.
// grid (12 h, 8 b); 64 threads, d = lane.
// ---------------------------------------------------------------------------
__global__ __launch_bounds__(64) void mod_reduce_ln(const float* __restrict__ partials,
                                                    const float* __restrict__ gamma,
                                                    const float* __restrict__ beta,
                                                    float* __restrict__ mod) {
  const int h = blockIdx.x, b = blockIdx.y;
  const int d = threadIdx.x;

  const float* p = partials + ((size_t)(b * 32) * 12 + h) * 64 + d;
  float s = 0.f;
#pragma unroll 8
  for (int mb = 0; mb < 32; mb++) s += p[(size_t)mb * 12 * 64];

  float sum = s, sumsq = s * s;
#pragma unroll
  for (int o = 32; o > 0; o >>= 1) {
    sum   += __shfl_xor(sum, o);
    sumsq += __shfl_xor(sumsq, o);
  }
  const float mu  = sum * (1.f / 64.f);
  const float var = sumsq * (1.f / 64.f) - mu * mu;
  const float r   = rsqrtf(var + LN_EPS);
  mod[(b * 12 + h) * 64 + d] = (s - mu) * r * gamma[d] + beta[d];
}

// ---------------------------------------------------------------------------
// Pass 2: q GEMM + fused modulation. Grid (6 nblk, 256 mblk).
// amod[m, c] = q[m, c] * p1[h(c), n(m)] * mod[b(m), c]  (bf16 out)
// ---------------------------------------------------------------------------
__global__ __launch_bounds__(256) void q_gemm_mod(const bf16* __restrict__ A,
                                                  const bf16* __restrict__ B,
                                                  const float* __restrict__ p1,
                                                  const float* __restrict__ mod,
                                                  bf16* __restrict__ amod) {
  __shared__ __align__(16) bf16 lA[128 * 64];
  __shared__ __align__(16) bf16 lB[128 * 64];
  f32x4 acc[4][4] = {};

  const int n0 = blockIdx.x * 128;
  const int m0 = blockIdx.y * 128;
  gemm_core_768(A + (size_t)m0 * 768, B + (size_t)n0 * 768, lA, lB, acc);

  const int tid = threadIdx.x, wave = tid >> 6, lane = tid & 63;
  const int row0 = m0 + (wave & 1) * 64 + (lane >> 4) * 4;
  const int col0 = n0 + (wave >> 1) * 64 + (lane & 15);
  const int b    = m0 >> 12;
  const int h    = (n0 + (wave >> 1) * 64) >> 6;   // wave-uniform head

  float p1v[4][4];
#pragma unroll
  for (int i = 0; i < 4; i++)
#pragma unroll
    for (int r = 0; r < 4; r++)
      p1v[i][r] = p1[h * 4096 + ((row0 + i * 16 + r) & 4095)];
  float mv[4];
#pragma unroll
  for (int j = 0; j < 4; j++) mv[j] = mod[b * 768 + col0 + j * 16];

#pragma unroll
  for (int i = 0; i < 4; i++)
#pragma unroll
    for (int j = 0; j < 4; j++)
#pragma unroll
      for (int r = 0; r < 4; r++)
        amod[(size_t)(row0 + i * 16 + r) * 768 + col0 + j * 16] =
            (bf16)(acc[i][j][r] * p1v[i][r] * mv[j]);
}

// ---------------------------------------------------------------------------
// Pass 3: out[32768,768] fp32 = amod @ w_proj_bf16^T + b_proj. Grid (6, 256).
// ---------------------------------------------------------------------------
__global__ __launch_bounds__(256) void gemm_proj(const bf16* __restrict__ A,
                                                 const bf16* __restrict__ B,
                                                 const float* __restrict__ bias,
                                                 float* __restrict__ C) {
  __shared__ __align__(16) bf16 lA[128 * 64];
  __shared__ __align__(16) bf16 lB[128 * 64];
  f32x4 acc[4][4] = {};

  const int n0 = blockIdx.x * 128;
  const int m0 = blockIdx.y * 128;
  gemm_core_768(A + (size_t)m0 * 768, B + (size_t)n0 * 768, lA, lB, acc);

  const int tid = threadIdx.x, wave = tid >> 6, lane = tid & 63;
  const int row0 = m0 + (wave & 1) * 64 + (lane >> 4) * 4;
  const int col0 = n0 + (wave >> 1) * 64 + (lane & 15);
#pragma unroll
  for (int j = 0; j < 4; j++) {
    const int col = col0 + j * 16;
    const float bv = bias[col];
#pragma unroll
    for (int i = 0; i < 4; i++)
#pragma unroll
      for (int r = 0; r < 4; r++)
        C[(size_t)(row0 + i * 16 + r) * 768 + col] = acc[i][j][r] + bv;
  }
}

// ---------------------------------------------------------------------------
extern "C" void kernel_launch(void* const* d_in, const int* in_sizes, int n_in,
                              void* d_out, int out_size, void* d_ws, size_t ws_size,
                              hipStream_t stream) {
  (void)in_sizes; (void)n_in; (void)out_size; (void)ws_size;

  const float* x      = (const float*)d_in[0];   // [8,4096,768]
  const float* w_qkv  = (const float*)d_in[1];   // [2304,768]
  const float* w_proj = (const float*)d_in[2];   // [768,768]
  const float* b_proj = (const float*)d_in[3];   // [768]
  const float* p1     = (const float*)d_in[4];   // [12,4096]
  const float* p2     = (const float*)d_in[5];   // [12,4096]
  const float* gamma  = (const float*)d_in[6];   // [64]
  const float* beta   = (const float*)d_in[7];   // [64]
  float* out = (float*)d_out;                    // [8,4096,768] fp32

  char* ws = (char*)d_ws;
  // workspace layout (bytes); total ~107 MB
  bf16*  xb       = (bf16*)(ws + 0);              // 50,331,648  x bf16 [32768,768]
  bf16*  wqb      = (bf16*)(ws + 50331648);       //  3,538,944  w_qkv bf16
  bf16*  wpb      = (bf16*)(ws + 53870592);       //  1,179,648  w_proj bf16
  bf16*  amod     = (bf16*)(ws + 55050240);       // 50,331,648  amod bf16 [32768,768]
  float* partials = (float*)(ws + 105381888);     //    786,432  [256][12][64] f32
  float* mod      = (float*)(ws + 106168320);     //     24,576  [8][12][64] f32

  // 1) all fp32 -> bf16 conversions in one launch (13,440 blocks exact)
  cvt_all<<<13440, 256, 0, stream>>>(x, w_qkv, w_proj, xb, wqb, wpb);

  // 2) k/v GEMM + fused p2*k*v reduction (k,v never written to HBM)
  kv_gemm_reduce<<<dim3(12, 256), 256, 0, stream>>>(xb, wqb, p2, partials);

  // 3) finish reduction + LayerNorm -> mod [8,12,64]
  mod_reduce_ln<<<dim3(12, 8), 64, 0, stream>>>(partials, gamma, beta, mod);

  // 4) q GEMM + fused p1/mod modulation -> amod bf16
  q_gemm_mod<<<dim3(6, 256), 256, 0, stream>>>(xb, wqb, p1, mod, amod);

  // 5) proj GEMM + bias -> out fp32
  gemm_proj<<<dim3(6, 256), 256, 0, stream>>>(amod, wpb, b_proj, out);
}